// Round 6
// baseline (6898.331 us; speedup 1.0000x reference)
//
#include <hip/hip_runtime.h>
#include <math.h>

#define B 128
#define N 1000
#define NP 1024
#define D 128
#define STEPS 64
#define NEG_INF (-INFINITY)
#define OUT_NEG (-1.0e30f)   // finite stand-in for -inf in OUTPUT only
#define MINIT   (-1.0e30f)   // finite init for online-softmax running max

// ---------------- ws layout (floats) ----------------
// fcPart    : B*8*128   per-(b,g) partial row sums for fixed_ctx
// fixed_ctx : B*D
// mQ, sQ    : B*4*8     per-(b,quarter,head) softmax partial max / sumexp
// waQ       : B*4*1024  per-(b,quarter): weighted-emb partial [h][d], scaled to mQ
// first_emb : B*D
// prev_emb  : B*D
// visited   : B*NP ints

// ============================================================
// fixed_ctx phase 1: partial sums of emb rows (8 groups of 125 rows per b)
// ============================================================
__global__ __launch_bounds__(256)
void fixed_part(const float* __restrict__ emb, float* __restrict__ fcPart) {
  const int b = blockIdx.x >> 3, g = blockIdx.x & 7;
  const int t = threadIdx.x, d = t & 127, half = t >> 7;
  __shared__ float part[256];
  float s = 0.f;
  for (int i = half; i < 125; i += 2)
    s += emb[((size_t)b * N + g * 125 + i) * D + d];
  part[t] = s;
  __syncthreads();
  if (t < 128) fcPart[(size_t)(b * 8 + g) * 128 + t] = part[t] + part[t + 128];
}

// ============================================================
// fixed_ctx phase 2: mean -> @ W_fixed
// ============================================================
__global__ __launch_bounds__(128)
void fixed_combine(const float* __restrict__ fcPart, const float* __restrict__ Wf,
                   float* __restrict__ fixed_ctx) {
  const int b = blockIdx.x, t = threadIdx.x;
  __shared__ float meanL[128];
  float s = 0.f;
  for (int g = 0; g < 8; ++g) s += fcPart[(size_t)(b * 8 + g) * 128 + t];
  meanL[t] = s * (1.0f / 1000.0f);
  __syncthreads();
  float a = 0.f;
  for (int k = 0; k < 128; ++k) a += meanL[k] * Wf[k * 128 + t];
  fixed_ctx[b * 128 + t] = a;
}

// ============================================================
// glimpseQ: grid B*4, block 256 (4 waves). Per (b, quarter):
// q = fixed + ctx@Wstep; qk_h = back-projected query (compat reads RAW emb);
// single-pass ONLINE softmax fused with weighted-emb accumulation over the
// quarter's 256 rows; hierarchical (m,s)-merge (r-lanes -> waves) and write
// per-quarter partials mQ/sQ/waQ. Sequential state is only READ here
// (visited, first/prev) — all writes of it stay in logits_kernel.
// ============================================================
__global__ __launch_bounds__(256)
void glimpseQ(const float* __restrict__ emb, const float* __restrict__ Wn,
              const float* __restrict__ Wstep, const float* __restrict__ Wp,
              const float* __restrict__ fixed_ctx,
              const float* __restrict__ first_emb, const float* __restrict__ prev_emb,
              const int* __restrict__ visited,
              float* __restrict__ mQ, float* __restrict__ sQ, float* __restrict__ waQ,
              int step) {
  const int b = blockIdx.x >> 2, q = blockIdx.x & 3;
  const int t = threadIdx.x, lane = t & 63, wv = t >> 6;
  const int r = (lane >> 4) & 3, c = lane & 15;

  __shared__ float ctxL[256];
  __shared__ float qL[128];
  __shared__ float qkL[8][128];
  __shared__ float waW[4][8][128];   // 16 KB wave partials
  __shared__ float mW[4][8], sW[4][8], fL[4][8];

  // ---- stage step context ----
  {
    float v;
    if (step == 0) v = Wp[t];
    else v = (t < 128) ? first_emb[b * D + t] : prev_emb[b * D + (t - 128)];
    ctxL[t] = v;
  }
  __syncthreads();

  // ---- q = fixed_ctx + ctx @ W_step ----
  if (t < 128) {
    float a = fixed_ctx[b * D + t];
    for (int i = 0; i < 256; ++i) a += ctxL[i] * Wstep[i * D + t];
    qL[t] = a;
  }
  __syncthreads();

  // ---- qk[h][d] = 0.25 * sum_k q[h*16+k] * Wk[d][h*16+k] ----
  {
    int d = t >> 1, h0 = (t & 1) * 4;
#pragma unroll
    for (int u = 0; u < 4; ++u) {
      int hh = h0 + u;
      float a = 0.f;
#pragma unroll
      for (int k = 0; k < 16; ++k) a += qL[hh * 16 + k] * Wn[(size_t)d * 384 + hh * 16 + k];
      qkL[hh][d] = a * 0.25f;   // 1/sqrt(dk)
    }
  }
  __syncthreads();

  float qkr[8][8];
#pragma unroll
  for (int h = 0; h < 8; ++h)
#pragma unroll
    for (int j = 0; j < 8; ++j) qkr[h][j] = qkL[h][c * 8 + j];

  float m[8], ss[8], wa[8][8];
#pragma unroll
  for (int h = 0; h < 8; ++h) {
    m[h] = MINIT; ss[h] = 0.f;
#pragma unroll
    for (int j = 0; j < 8; ++j) wa[h][j] = 0.f;
  }

  const float4* emb4 = (const float4*)emb;
  for (int it = 0; it < 16; ++it) {
    int n = q * 256 + it * 16 + wv * 4 + r;
    bool inb = (n < N);
    float4 e0 = make_float4(0.f, 0.f, 0.f, 0.f), e1 = e0;
    if (inb) {
      e0 = emb4[((size_t)b * N + n) * 32 + c * 2];
      e1 = emb4[((size_t)b * N + n) * 32 + c * 2 + 1];
    }
    float e_[8] = {e0.x, e0.y, e0.z, e0.w, e1.x, e1.y, e1.z, e1.w};
    float s[8];
#pragma unroll
    for (int h = 0; h < 8; ++h) {
      s[h] = qkr[h][0] * e_[0] + qkr[h][1] * e_[1] + qkr[h][2] * e_[2] + qkr[h][3] * e_[3]
           + qkr[h][4] * e_[4] + qkr[h][5] * e_[5] + qkr[h][6] * e_[6] + qkr[h][7] * e_[7];
    }
#pragma unroll
    for (int off = 1; off <= 8; off <<= 1)
#pragma unroll
      for (int h = 0; h < 8; ++h) s[h] += __shfl_xor(s[h], off);

    bool vis = !inb || (visited[b * NP + n] != 0);
#pragma unroll
    for (int h = 0; h < 8; ++h) {
      float sv = vis ? MINIT : s[h];
      float mn = fmaxf(m[h], sv);
      float fo = expf(m[h] - mn);          // 1 when max unchanged; 0 on first real row
      float p  = vis ? 0.f : expf(s[h] - mn);
      ss[h] = ss[h] * fo + p;
#pragma unroll
      for (int j = 0; j < 8; ++j) wa[h][j] = wa[h][j] * fo + p * e_[j];
      m[h] = mn;
    }
  }

  // ---- merge across the 4 r-lane groups (xor 16, 32) ----
#pragma unroll
  for (int off = 16; off <= 32; off <<= 1) {
#pragma unroll
    for (int h = 0; h < 8; ++h) {
      float mo = __shfl_xor(m[h], off);
      float so = __shfl_xor(ss[h], off);
      float mn = fmaxf(m[h], mo);
      float fa = expf(m[h] - mn), fb = expf(mo - mn);
      ss[h] = ss[h] * fa + so * fb;
#pragma unroll
      for (int j = 0; j < 8; ++j)
        wa[h][j] = wa[h][j] * fa + __shfl_xor(wa[h][j], off) * fb;
      m[h] = mn;
    }
  }

  // ---- wave partials to LDS ----
  if (lane < 16) {
#pragma unroll
    for (int h = 0; h < 8; ++h)
#pragma unroll
      for (int j = 0; j < 8; ++j) waW[wv][h][c * 8 + j] = wa[h][j];
  }
  if (lane == 0) {
#pragma unroll
    for (int h = 0; h < 8; ++h) { mW[wv][h] = m[h]; sW[wv][h] = ss[h]; }
  }
  __syncthreads();

  // ---- merge 4 waves -> quarter partials ----
  if (t < 8) {
    float mq = fmaxf(fmaxf(mW[0][t], mW[1][t]), fmaxf(mW[2][t], mW[3][t]));
    float sq = 0.f;
#pragma unroll
    for (int w = 0; w < 4; ++w) {
      float f = expf(mW[w][t] - mq);
      fL[w][t] = f;
      sq += sW[w][t] * f;
    }
    mQ[(b * 4 + q) * 8 + t] = mq;
    sQ[(b * 4 + q) * 8 + t] = sq;
  }
  __syncthreads();
  for (int idx = t; idx < 1024; idx += 256) {
    int h = idx >> 7, d = idx & 127;
    float a = waW[0][h][d] * fL[0][h] + waW[1][h][d] * fL[1][h]
            + waW[2][h][d] * fL[2][h] + waW[3][h][d] * fL[3][h];
    waQ[(size_t)(b * 4 + q) * 1024 + idx] = a;
  }
}

// ============================================================
// logits_kernel: grid B, block 256 (4 waves). Per b: merge quarter partials
// -> weN -> heads -> glimpse -> lq (logit query in emb space) -> logits over
// all 1024 rows via lq.emb (distributed dot) -> tanh clip, mask, log_softmax,
// argmax, state update, outputs. ALL sequential state lives here.
// ============================================================
__global__ __launch_bounds__(256)
void logits_kernel(const float* __restrict__ emb, const float* __restrict__ Wn,
                   const float* __restrict__ W_out,
                   const float* __restrict__ mQ, const float* __restrict__ sQ,
                   const float* __restrict__ waQ,
                   int* __restrict__ visited, float* __restrict__ first_emb,
                   float* __restrict__ prev_emb, float* __restrict__ out, int step) {
  const int b = blockIdx.x;
  const int t = threadIdx.x;
  const int lane = t & 63, wid = t >> 6;
  const int r = (lane >> 4) & 3, c = lane & 15;

  __shared__ float eQL[4][8];
  __shared__ float invSL[8];
  __shared__ float weN[8][128];
  __shared__ float headsL[128];
  __shared__ float gl[128];
  __shared__ float lqL[128];
  __shared__ float lvL[1024];
  __shared__ float redV[4];
  __shared__ int   redI[4];
  __shared__ float mS;
  __shared__ int   selS;

  // ---- merge 4 quarter softmax partials ----
  if (t < 8) {
    float m0 = mQ[(b * 4 + 0) * 8 + t], m1 = mQ[(b * 4 + 1) * 8 + t];
    float m2 = mQ[(b * 4 + 2) * 8 + t], m3 = mQ[(b * 4 + 3) * 8 + t];
    float M = fmaxf(fmaxf(m0, m1), fmaxf(m2, m3));
    float e0 = expf(m0 - M), e1 = expf(m1 - M), e2 = expf(m2 - M), e3 = expf(m3 - M);
    float S = sQ[(b * 4 + 0) * 8 + t] * e0 + sQ[(b * 4 + 1) * 8 + t] * e1
            + sQ[(b * 4 + 2) * 8 + t] * e2 + sQ[(b * 4 + 3) * 8 + t] * e3;
    eQL[0][t] = e0; eQL[1][t] = e1; eQL[2][t] = e2; eQL[3][t] = e3;
    invSL[t] = 1.0f / S;
  }
  __syncthreads();
  for (int idx = t; idx < 1024; idx += 256) {
    int h = idx >> 7;
    float w = waQ[(size_t)(b * 4 + 0) * 1024 + idx] * eQL[0][h]
            + waQ[(size_t)(b * 4 + 1) * 1024 + idx] * eQL[1][h]
            + waQ[(size_t)(b * 4 + 2) * 1024 + idx] * eQL[2][h]
            + waQ[(size_t)(b * 4 + 3) * 1024 + idx] * eQL[3][h];
    weN[h][idx & 127] = w * invSL[h];
  }
  __syncthreads();

  // ---- heads[h*16+k] = sum_d weN[h][d] * Wv[d][h*16+k] ----
  if (t < 128) {
    int h = t >> 4, k = t & 15;
    float a = 0.f;
    for (int d = 0; d < 128; ++d) a += weN[h][d] * Wn[(size_t)d * 384 + 128 + h * 16 + k];
    headsL[t] = a;
  }
  __syncthreads();
  // ---- glimpse = heads @ W_out ----
  if (t < 128) {
    float a = 0.f;
    for (int k = 0; k < 128; ++k) a += headsL[k] * W_out[k * 128 + t];
    gl[t] = a;
  }
  __syncthreads();
  // ---- lq[d] = (1/sqrt(D)) * sum_e gl[e] * W3[d][e] ----
  if (t < 128) {
    float a = 0.f;
    const float4* w4 = (const float4*)(Wn + (size_t)t * 384 + 256);
    const float4* g4 = (const float4*)gl;
    for (int e = 0; e < 32; ++e) {
      float4 ww = w4[e]; float4 gg = g4[e];
      a += ww.x * gg.x + ww.y * gg.y + ww.z * gg.z + ww.w * gg.w;
    }
    lqL[t] = a * 0.08838834764831845f;  // 1/sqrt(128)
  }
  __syncthreads();

  // ---- logits over 1024 rows: distributed dot lq . emb[n] ----
  float lq0[8];
#pragma unroll
  for (int j = 0; j < 8; ++j) lq0[j] = lqL[c * 8 + j];
  const float4* emb4 = (const float4*)emb;
  for (int it = 0; it < 64; ++it) {
    int nl = it * 16 + wid * 4 + r;
    float4 e0 = make_float4(0.f, 0.f, 0.f, 0.f), e1 = e0;
    if (nl < N) {
      e0 = emb4[((size_t)b * N + nl) * 32 + c * 2];
      e1 = emb4[((size_t)b * N + nl) * 32 + c * 2 + 1];
    }
    float s = lq0[0] * e0.x + lq0[1] * e0.y + lq0[2] * e0.z + lq0[3] * e0.w
            + lq0[4] * e1.x + lq0[5] * e1.y + lq0[6] * e1.z + lq0[7] * e1.w;
#pragma unroll
    for (int off = 1; off <= 8; off <<= 1) s += __shfl_xor(s, off);
    if (c == 0) {
      bool vis = (nl >= N) || (visited[b * NP + nl] != 0);
      lvL[nl] = vis ? NEG_INF : 10.f * tanhf(s);
    }
  }
  __syncthreads();

  // ---- log_softmax + argmax + state update (round-5 proven block) ----
  float lv[4];
  int ok[4];
#pragma unroll
  for (int j = 0; j < 4; ++j) {
    float v = lvL[t * 4 + j];
    lv[j] = v;
    ok[j] = (v != NEG_INF);
  }

  float bv = lv[0];
  int bi = t * 4;
#pragma unroll
  for (int j = 1; j < 4; ++j)
    if (lv[j] > bv) { bv = lv[j]; bi = t * 4 + j; }
#pragma unroll
  for (int off = 32; off >= 1; off >>= 1) {
    float ov = __shfl_xor(bv, off);
    int oi = __shfl_xor(bi, off);
    if (ov > bv || (ov == bv && oi < bi)) { bv = ov; bi = oi; }
  }
  if (lane == 0) { redV[wid] = bv; redI[wid] = bi; }
  __syncthreads();
  if (t == 0) {
    float mv = redV[0]; int mi = redI[0];
    for (int w = 1; w < 4; ++w)
      if (redV[w] > mv || (redV[w] == mv && redI[w] < mi)) { mv = redV[w]; mi = redI[w]; }
    mS = mv; selS = mi;
  }
  __syncthreads();
  const float m = mS;

  float se = 0.f;
#pragma unroll
  for (int j = 0; j < 4; ++j) if (ok[j]) se += expf(lv[j] - m);
#pragma unroll
  for (int off = 32; off >= 1; off >>= 1) se += __shfl_xor(se, off);
  __syncthreads();                  // reads of redV (argmax) complete
  if (lane == 0) redV[wid] = se;
  __syncthreads();
  se = redV[0] + redV[1] + redV[2] + redV[3];
  const float lse = m + logf(se);

  if (t < 250) {
    float4 o;
    o.x = ok[0] ? (lv[0] - lse) : OUT_NEG;
    o.y = ok[1] ? (lv[1] - lse) : OUT_NEG;
    o.z = ok[2] ? (lv[2] - lse) : OUT_NEG;
    o.w = ok[3] ? (lv[3] - lse) : OUT_NEG;
    ((float4*)(out + ((size_t)b * STEPS + step) * N))[t] = o;
  }

  const int sel = selS;
  if (t == 0) {
    out[(size_t)B * STEPS * N + b * STEPS + step] = (float)sel;
    visited[b * NP + sel] = 1;
  }
  if (t < 128) {
    float e = emb[((size_t)b * N + sel) * D + t];
    prev_emb[b * D + t] = e;
    if (step == 0) first_emb[b * D + t] = e;
  }
}

// ============================================================
extern "C" void kernel_launch(void* const* d_in, const int* in_sizes, int n_in,
                              void* d_out, int out_size, void* d_ws, size_t ws_size,
                              hipStream_t stream) {
  (void)in_sizes; (void)n_in; (void)out_size; (void)ws_size;
  const float* emb     = (const float*)d_in[0];
  const float* W_node  = (const float*)d_in[1];
  const float* W_fixed = (const float*)d_in[2];
  const float* W_step  = (const float*)d_in[3];
  const float* W_out   = (const float*)d_in[4];
  const float* Wp      = (const float*)d_in[5];
  float* out = (float*)d_out;
  float* ws  = (float*)d_ws;

  float* fcPart    = ws;
  float* fixed_ctx = fcPart + (size_t)B * 8 * 128;
  float* mQ        = fixed_ctx + (size_t)B * D;
  float* sQ        = mQ + (size_t)B * 4 * 8;
  float* waQ       = sQ + (size_t)B * 4 * 8;
  float* first_emb = waQ + (size_t)B * 4 * 1024;
  float* prev_emb  = first_emb + (size_t)B * D;
  int*   visited   = (int*)(prev_emb + (size_t)B * D);

  hipMemsetAsync(visited, 0, (size_t)B * NP * sizeof(int), stream);
  fixed_part<<<B * 8, 256, 0, stream>>>(emb, fcPart);
  fixed_combine<<<B, 128, 0, stream>>>(fcPart, W_fixed, fixed_ctx);
  for (int s = 0; s < STEPS; ++s) {
    glimpseQ<<<B * 4, 256, 0, stream>>>(emb, W_node, W_step, Wp, fixed_ctx,
                                        first_emb, prev_emb, visited, mQ, sQ, waQ, s);
    logits_kernel<<<B, 256, 0, stream>>>(emb, W_node, W_out, mQ, sQ, waQ,
                                         visited, first_emb, prev_emb, out, s);
  }
}

// Round 7
// 5023.979 us; speedup vs baseline: 1.3731x; 1.3731x over previous
//
#include <hip/hip_runtime.h>
#include <math.h>

#define B 128
#define N 1000
#define NP 1024
#define D 128
#define STEPS 64
#define NEG_INF (-INFINITY)
#define OUT_NEG (-1.0e30f)   // finite stand-in for -inf in OUTPUT only

// ---------------- ws layout (floats) ----------------
// fcPart    : B*8*128
// fixed_ctx : B*D
// mE, sE    : B*8*8      per-(b,g,head) block-softmax partial max / sumexp
// waE       : B*8*1024   per-(b,g): weighted-emb partial [h][d], scaled by exp(c-mE)
// lKt       : B*D*NP     logitK transposed [b][d][n]
// first_emb : B*D
// prev_emb  : B*D
// visited   : B*NP ints

// ============================================================
// Precompute lKt: lK = emb @ W_node[:,256:384], stored transposed. (round-5 proven)
// ============================================================
__global__ __launch_bounds__(256)
void precompute_lkt(const float* __restrict__ emb, const float* __restrict__ Wn,
                    float* __restrict__ lKt) {
  const int rt = blockIdx.x;
  const int t  = threadIdx.x;
  const int tx = t & 15, ty = t >> 4;
  __shared__ float4 wL[64 * 32];

  float acc[8][8];
#pragma unroll
  for (int i = 0; i < 8; ++i)
#pragma unroll
    for (int j = 0; j < 8; ++j) acc[i][j] = 0.f;

  const float4* Wn4 = (const float4*)Wn;
  const float* ebase = emb + (size_t)(rt * 128 + ty * 8) * 128;

  for (int kk = 0; kk < 2; ++kk) {
    __syncthreads();
    for (int idx = t; idx < 64 * 32; idx += 256) {
      int dl = idx >> 5, c4 = idx & 31;
      wL[dl * 32 + c4] = Wn4[(size_t)(kk * 64 + dl) * 96 + 64 + c4];
    }
    __syncthreads();
    for (int dl = 0; dl < 64; dl += 4) {
      float4 e4[8];
#pragma unroll
      for (int i = 0; i < 8; ++i)
        e4[i] = *(const float4*)(ebase + (size_t)i * 128 + kk * 64 + dl);
#pragma unroll
      for (int dd = 0; dd < 4; ++dd) {
        float4 w0 = wL[(dl + dd) * 32 + tx * 2];
        float4 w1 = wL[(dl + dd) * 32 + tx * 2 + 1];
        float w_[8] = {w0.x, w0.y, w0.z, w0.w, w1.x, w1.y, w1.z, w1.w};
        float e_[8] = {
          dd == 0 ? e4[0].x : dd == 1 ? e4[0].y : dd == 2 ? e4[0].z : e4[0].w,
          dd == 0 ? e4[1].x : dd == 1 ? e4[1].y : dd == 2 ? e4[1].z : e4[1].w,
          dd == 0 ? e4[2].x : dd == 1 ? e4[2].y : dd == 2 ? e4[2].z : e4[2].w,
          dd == 0 ? e4[3].x : dd == 1 ? e4[3].y : dd == 2 ? e4[3].z : e4[3].w,
          dd == 0 ? e4[4].x : dd == 1 ? e4[4].y : dd == 2 ? e4[4].z : e4[4].w,
          dd == 0 ? e4[5].x : dd == 1 ? e4[5].y : dd == 2 ? e4[5].z : e4[5].w,
          dd == 0 ? e4[6].x : dd == 1 ? e4[6].y : dd == 2 ? e4[6].z : e4[6].w,
          dd == 0 ? e4[7].x : dd == 1 ? e4[7].y : dd == 2 ? e4[7].z : e4[7].w};
#pragma unroll
        for (int i = 0; i < 8; ++i)
#pragma unroll
          for (int j = 0; j < 8; ++j) acc[i][j] += e_[i] * w_[j];
      }
    }
  }

#pragma unroll
  for (int i = 0; i < 8; ++i) {
    int row = rt * 128 + ty * 8 + i;
    int b = row / 1000;
    int n = row - b * 1000;
#pragma unroll
    for (int j = 0; j < 8; ++j)
      lKt[((size_t)b * D + tx * 8 + j) * NP + n] = acc[i][j];
  }
}

// ============================================================
// fixed_ctx phase 1 + 2 (round-6 proven)
// ============================================================
__global__ __launch_bounds__(256)
void fixed_part(const float* __restrict__ emb, float* __restrict__ fcPart) {
  const int b = blockIdx.x >> 3, g = blockIdx.x & 7;
  const int t = threadIdx.x, d = t & 127, half = t >> 7;
  __shared__ float part[256];
  float s = 0.f;
  for (int i = half; i < 125; i += 2)
    s += emb[((size_t)b * N + g * 125 + i) * D + d];
  part[t] = s;
  __syncthreads();
  if (t < 128) fcPart[(size_t)(b * 8 + g) * 128 + t] = part[t] + part[t + 128];
}

__global__ __launch_bounds__(128)
void fixed_combine(const float* __restrict__ fcPart, const float* __restrict__ Wf,
                   float* __restrict__ fixed_ctx) {
  const int b = blockIdx.x, t = threadIdx.x;
  __shared__ float meanL[128];
  float s = 0.f;
  for (int g = 0; g < 8; ++g) s += fcPart[(size_t)(b * 8 + g) * 128 + t];
  meanL[t] = s * (1.0f / 1000.0f);
  __syncthreads();
  float a = 0.f;
  for (int k = 0; k < 128; ++k) a += meanL[k] * Wf[k * 128 + t];
  fixed_ctx[b * 128 + t] = a;
}

// ============================================================
// glimpseE: grid B*8, block 256 (4 waves). Per (b, g): 128 rows.
// Two-pass softmax: pass1 compat -> LDS, block max per head, exp once;
// pass2 weighted-emb accumulate. Writes mE/sE/waE partials.
// Only READS sequential state (visited, first/prev).
// ============================================================
__global__ __launch_bounds__(256)
void glimpseE(const float* __restrict__ emb, const float* __restrict__ Wn,
              const float* __restrict__ Wstep, const float* __restrict__ Wp,
              const float* __restrict__ fixed_ctx,
              const float* __restrict__ first_emb, const float* __restrict__ prev_emb,
              const int* __restrict__ visited,
              float* __restrict__ mE, float* __restrict__ sE, float* __restrict__ waE,
              int step) {
  const int b = blockIdx.x >> 3, g = blockIdx.x & 7;
  const int t = threadIdx.x, lane = t & 63, wv = t >> 6;
  const int r = (lane >> 4) & 3, c = lane & 15;

  __shared__ float ctxL[256];
  __shared__ float qL[128];
  __shared__ float qkL[8][128];
  __shared__ float cB[8][128];      // compat, then p
  __shared__ float waW[4][1024];    // 16 KB wave partials
  __shared__ float mH[8], sH[8];

  // ---- stage step context ----
  {
    float v;
    if (step == 0) v = Wp[t];
    else v = (t < 128) ? first_emb[b * D + t] : prev_emb[b * D + (t - 128)];
    ctxL[t] = v;
  }
  __syncthreads();

  // ---- q = fixed_ctx + ctx @ W_step ----
  if (t < 128) {
    float a = fixed_ctx[b * D + t];
    for (int i = 0; i < 256; ++i) a += ctxL[i] * Wstep[i * D + t];
    qL[t] = a;
  }
  __syncthreads();

  // ---- qk[h][d] = 0.25 * sum_k q[h*16+k] * Wk[d][h*16+k] ----
  {
    int d = t >> 1, h0 = (t & 1) * 4;
#pragma unroll
    for (int u = 0; u < 4; ++u) {
      int hh = h0 + u;
      float a = 0.f;
#pragma unroll
      for (int k = 0; k < 16; ++k) a += qL[hh * 16 + k] * Wn[(size_t)d * 384 + hh * 16 + k];
      qkL[hh][d] = a * 0.25f;
    }
  }
  __syncthreads();

  float qkr[8][8];
#pragma unroll
  for (int h = 0; h < 8; ++h)
#pragma unroll
    for (int j = 0; j < 8; ++j) qkr[h][j] = qkL[h][c * 8 + j];

  const float4* emb4 = (const float4*)emb;

  // ---- pass 1: compat -> cB ----
  for (int it = 0; it < 8; ++it) {
    int nl = it * 16 + wv * 4 + r;          // 0..127
    int n = g * 128 + nl;
    float4 e0 = make_float4(0.f, 0.f, 0.f, 0.f), e1 = e0;
    if (n < N) {
      e0 = emb4[((size_t)b * N + n) * 32 + c * 2];
      e1 = emb4[((size_t)b * N + n) * 32 + c * 2 + 1];
    }
    float s[8];
#pragma unroll
    for (int h = 0; h < 8; ++h) {
      s[h] = qkr[h][0] * e0.x + qkr[h][1] * e0.y + qkr[h][2] * e0.z + qkr[h][3] * e0.w
           + qkr[h][4] * e1.x + qkr[h][5] * e1.y + qkr[h][6] * e1.z + qkr[h][7] * e1.w;
    }
#pragma unroll
    for (int off = 1; off <= 8; off <<= 1)
#pragma unroll
      for (int h = 0; h < 8; ++h) s[h] += __shfl_xor(s[h], off);
    if (c == 0) {
      bool vis = (n >= N) || (visited[b * NP + n] != 0);
#pragma unroll
      for (int h = 0; h < 8; ++h) cB[h][nl] = vis ? NEG_INF : s[h];
    }
  }
  __syncthreads();

  // ---- per-head block max (wave wv handles heads 2wv, 2wv+1) ----
#pragma unroll
  for (int u = 0; u < 2; ++u) {
    int h = wv * 2 + u;
    float m = fmaxf(cB[h][lane], cB[h][lane + 64]);
#pragma unroll
    for (int off = 1; off <= 32; off <<= 1) m = fmaxf(m, __shfl_xor(m, off));
    if (lane == 0) mH[h] = m;
  }
  __syncthreads();

  // ---- exp in place ----
  float* cBf = &cB[0][0];
#pragma unroll
  for (int u = 0; u < 4; ++u) {
    int idx = t + u * 256;
    float v = cBf[idx];
    cBf[idx] = (v == NEG_INF) ? 0.f : expf(v - mH[idx >> 7]);
  }
  __syncthreads();

  // ---- per-head sum ----
#pragma unroll
  for (int u = 0; u < 2; ++u) {
    int h = wv * 2 + u;
    float s = cB[h][lane] + cB[h][lane + 64];
#pragma unroll
    for (int off = 1; off <= 32; off <<= 1) s += __shfl_xor(s, off);
    if (lane == 0) sH[h] = s;
  }

  // ---- pass 2: weighted emb accumulate ----
  float wa[8][8];
#pragma unroll
  for (int h = 0; h < 8; ++h)
#pragma unroll
    for (int j = 0; j < 8; ++j) wa[h][j] = 0.f;

  for (int it = 0; it < 8; ++it) {
    int nl = it * 16 + wv * 4 + r;
    int n = g * 128 + nl;
    if (n < N) {
      float4 e0 = emb4[((size_t)b * N + n) * 32 + c * 2];
      float4 e1 = emb4[((size_t)b * N + n) * 32 + c * 2 + 1];
#pragma unroll
      for (int h = 0; h < 8; ++h) {
        float p = cB[h][nl];
        wa[h][0] += p * e0.x; wa[h][1] += p * e0.y;
        wa[h][2] += p * e0.z; wa[h][3] += p * e0.w;
        wa[h][4] += p * e1.x; wa[h][5] += p * e1.y;
        wa[h][6] += p * e1.z; wa[h][7] += p * e1.w;
      }
    }
  }
  // reduce over the 4 r-lane groups
#pragma unroll
  for (int h = 0; h < 8; ++h)
#pragma unroll
    for (int j = 0; j < 8; ++j) {
      wa[h][j] += __shfl_xor(wa[h][j], 16);
      wa[h][j] += __shfl_xor(wa[h][j], 32);
    }
  if (lane < 16) {
#pragma unroll
    for (int h = 0; h < 8; ++h)
#pragma unroll
      for (int j = 0; j < 8; ++j) waW[wv][h * 128 + c * 8 + j] = wa[h][j];
  }
  __syncthreads();

  // ---- write partials ----
#pragma unroll
  for (int u = 0; u < 4; ++u) {
    int idx = t + u * 256;
    waE[(size_t)(b * 8 + g) * 1024 + idx] =
        waW[0][idx] + waW[1][idx] + waW[2][idx] + waW[3][idx];
  }
  if (t < 8) {
    mE[(b * 8 + g) * 8 + t] = mH[t];
    sE[(b * 8 + g) * 8 + t] = sH[t];
  }
}

// ============================================================
// logitsK: grid B, block 1024 (16 waves). Merge 8 partials -> weN -> heads
// -> glimpse (scaled) -> logits via lKt (d-quarter split, float4 along n)
// -> tanh/mask/log_softmax/argmax/state update. ALL sequential state here.
// ============================================================
__global__ __launch_bounds__(1024)
void logitsK(const float* __restrict__ emb, const float* __restrict__ Wn,
             const float* __restrict__ W_out, const float* __restrict__ lKt,
             const float* __restrict__ mE, const float* __restrict__ sE,
             const float* __restrict__ waE,
             int* __restrict__ visited, float* __restrict__ first_emb,
             float* __restrict__ prev_emb, float* __restrict__ out, int step) {
  const int b = blockIdx.x;
  const int t = threadIdx.x;
  const int lane = t & 63, wid = t >> 6;

  __shared__ float fH[8][8];     // [g][h]
  __shared__ float invS[8];
  __shared__ float weN[8][128];
  __shared__ float headsL[128];
  __shared__ float glS[128];
  __shared__ float lvP[4][1024]; // 16 KB d-quarter partials
  __shared__ float redV[4];
  __shared__ int   redI[4];
  __shared__ float mS;
  __shared__ int   selS;

  // ---- merge softmax partials ----
  if (t < 8) {
    float M = NEG_INF;
    for (int g = 0; g < 8; ++g) M = fmaxf(M, mE[(b * 8 + g) * 8 + t]);
    float S = 0.f;
    for (int g = 0; g < 8; ++g) {
      float f = expf(mE[(b * 8 + g) * 8 + t] - M);
      fH[g][t] = f;
      S += sE[(b * 8 + g) * 8 + t] * f;
    }
    invS[t] = 1.0f / S;
  }
  __syncthreads();
  {
    int h = t >> 7;
    float w = 0.f;
    for (int g = 0; g < 8; ++g) w += waE[(size_t)(b * 8 + g) * 1024 + t] * fH[g][h];
    weN[h][t & 127] = w * invS[h];
  }
  __syncthreads();

  // ---- heads: o = t>>3, 8 threads per output, 16 d each ----
  {
    int o = t >> 3, sl = t & 7, h = o >> 4;
    float a = 0.f;
#pragma unroll
    for (int dd = 0; dd < 16; ++dd) {
      int d = sl * 16 + dd;
      a += weN[h][d] * Wn[(size_t)d * 384 + 128 + o];
    }
    a += __shfl_xor(a, 1); a += __shfl_xor(a, 2); a += __shfl_xor(a, 4);
    if (sl == 0) headsL[o] = a;
  }
  __syncthreads();
  // ---- glimpse (scaled by 1/sqrt(D)) ----
  {
    int o = t >> 3, sl = t & 7;
    float a = 0.f;
#pragma unroll
    for (int kk = 0; kk < 16; ++kk) {
      int k = sl * 16 + kk;
      a += headsL[k] * W_out[k * 128 + o];
    }
    a += __shfl_xor(a, 1); a += __shfl_xor(a, 2); a += __shfl_xor(a, 4);
    if (sl == 0) glS[o] = a * 0.08838834764831845f;
  }
  __syncthreads();

  // ---- logits: d-quarter dq = t>>8, n-slot tn = t&255 (float4 along n) ----
  {
    int dq = t >> 8, tn = t & 255;
    const float4* lk4 = (const float4*)(lKt + (size_t)b * D * NP);
    float a0 = 0.f, a1 = 0.f, a2 = 0.f, a3 = 0.f;
#pragma unroll 4
    for (int dd = 0; dd < 32; ++dd) {
      int d = dq * 32 + dd;
      float gv = glS[d];
      float4 v = lk4[d * 256 + tn];
      a0 += gv * v.x; a1 += gv * v.y; a2 += gv * v.z; a3 += gv * v.w;
    }
    lvP[dq][tn * 4 + 0] = a0;
    lvP[dq][tn * 4 + 1] = a1;
    lvP[dq][tn * 4 + 2] = a2;
    lvP[dq][tn * 4 + 3] = a3;
  }
  __syncthreads();

  // ---- finalize on t<256 (round-2 proven), others keep barriers ----
  float lv[4];
  int ok[4];
  if (t < 256) {
#pragma unroll
    for (int j = 0; j < 4; ++j) {
      int n = t * 4 + j;
      float a = lvP[0][n] + lvP[1][n] + lvP[2][n] + lvP[3][n];
      int valid = (n < N) && (visited[b * NP + n] == 0);
      float l = 10.f * tanhf(a);
      lv[j] = valid ? l : NEG_INF;
      ok[j] = valid;
    }
    float bv = lv[0];
    int bi = t * 4;
#pragma unroll
    for (int j = 1; j < 4; ++j)
      if (lv[j] > bv) { bv = lv[j]; bi = t * 4 + j; }
#pragma unroll
    for (int off = 32; off >= 1; off >>= 1) {
      float ov = __shfl_xor(bv, off);
      int oi = __shfl_xor(bi, off);
      if (ov > bv || (ov == bv && oi < bi)) { bv = ov; bi = oi; }
    }
    if (lane == 0) { redV[wid] = bv; redI[wid] = bi; }
  }
  __syncthreads();
  if (t == 0) {
    float mv = redV[0]; int mi = redI[0];
    for (int w = 1; w < 4; ++w)
      if (redV[w] > mv || (redV[w] == mv && redI[w] < mi)) { mv = redV[w]; mi = redI[w]; }
    mS = mv; selS = mi;
  }
  __syncthreads();
  const float m = mS;

  float se = 0.f;
  if (t < 256) {
#pragma unroll
    for (int j = 0; j < 4; ++j) if (ok[j]) se += expf(lv[j] - m);
#pragma unroll
    for (int off = 32; off >= 1; off >>= 1) se += __shfl_xor(se, off);
  }
  __syncthreads();                  // argmax reads of redV complete
  if (t < 256 && lane == 0) redV[wid] = se;
  __syncthreads();
  const float lse = m + logf(redV[0] + redV[1] + redV[2] + redV[3]);

  if (t < 250) {
    float4 o;
    o.x = ok[0] ? (lv[0] - lse) : OUT_NEG;
    o.y = ok[1] ? (lv[1] - lse) : OUT_NEG;
    o.z = ok[2] ? (lv[2] - lse) : OUT_NEG;
    o.w = ok[3] ? (lv[3] - lse) : OUT_NEG;
    ((float4*)(out + ((size_t)b * STEPS + step) * N))[t] = o;
  }

  const int sel = selS;
  if (t == 0) {
    out[(size_t)B * STEPS * N + b * STEPS + step] = (float)sel;
    visited[b * NP + sel] = 1;
  }
  if (t < 128) {
    float e = emb[((size_t)b * N + sel) * D + t];
    prev_emb[b * D + t] = e;
    if (step == 0) first_emb[b * D + t] = e;
  }
}

// ============================================================
extern "C" void kernel_launch(void* const* d_in, const int* in_sizes, int n_in,
                              void* d_out, int out_size, void* d_ws, size_t ws_size,
                              hipStream_t stream) {
  (void)in_sizes; (void)n_in; (void)out_size; (void)ws_size;
  const float* emb     = (const float*)d_in[0];
  const float* W_node  = (const float*)d_in[1];
  const float* W_fixed = (const float*)d_in[2];
  const float* W_step  = (const float*)d_in[3];
  const float* W_out   = (const float*)d_in[4];
  const float* Wp      = (const float*)d_in[5];
  float* out = (float*)d_out;
  float* ws  = (float*)d_ws;

  float* fcPart    = ws;
  float* fixed_ctx = fcPart + (size_t)B * 8 * 128;
  float* mEp       = fixed_ctx + (size_t)B * D;
  float* sEp       = mEp + (size_t)B * 8 * 8;
  float* waE       = sEp + (size_t)B * 8 * 8;
  float* lKt       = waE + (size_t)B * 8 * 1024;
  float* first_emb = lKt + (size_t)B * D * NP;
  float* prev_emb  = first_emb + (size_t)B * D;
  int*   visited   = (int*)(prev_emb + (size_t)B * D);

  hipMemsetAsync(visited, 0, (size_t)B * NP * sizeof(int), stream);
  precompute_lkt<<<1000, 256, 0, stream>>>(emb, W_node, lKt);
  fixed_part<<<B * 8, 256, 0, stream>>>(emb, fcPart);
  fixed_combine<<<B, 128, 0, stream>>>(fcPart, W_fixed, fixed_ctx);
  for (int s = 0; s < STEPS; ++s) {
    glimpseE<<<B * 8, 256, 0, stream>>>(emb, W_node, W_step, Wp, fixed_ctx,
                                        first_emb, prev_emb, visited,
                                        mEp, sEp, waE, s);
    logitsK<<<B, 1024, 0, stream>>>(emb, W_node, W_out, lKt, mEp, sEp, waE,
                                    visited, first_emb, prev_emb, out, s);
  }
}